// Round 1
// baseline (751.619 us; speedup 1.0000x reference)
//
#include <hip/hip_runtime.h>

#define HD 256
#define NCH 64
#define NB 16
#define NPC (NB * HD * HD)  // BN population per channel = 1048576

typedef __attribute__((ext_vector_type(4))) float f32x4;
typedef __attribute__((ext_vector_type(8))) short s16x8;
typedef __attribute__((ext_vector_type(4))) short s16x4;

__device__ __forceinline__ short f2bf(float f) {
    unsigned u = __float_as_uint(f);
    u += 0x7FFFu + ((u >> 16) & 1u);   // round-to-nearest-even
    return (short)(u >> 16);
}

// PASS 0: Gram * w, triu-masked, accumulate per-channel sum/sumsq into stats (no store).
// PASS 1: recompute Gram * w, normalize with stats, store to out. tile==3 writes the
//         constant lower-left region ((0-mean)*rstd*gamma+beta) without computing.
template <int PASS>
__global__ __launch_bounds__(256) void gram_bn_kernel(
    const float* __restrict__ x, const float* __restrict__ w,
    const float* __restrict__ gamma, const float* __restrict__ beta,
    float* __restrict__ out, float* __restrict__ stats)
{
    const int tile = blockIdx.x;   // 0:(0,0) 1:(0,1) 2:(1,1) 3:(1,0) [pass1 only]
    const int b    = blockIdx.y;   // batch
    const int c    = blockIdx.z;   // channel
    const int n    = b * NCH + c;
    const int tid  = threadIdx.x;

    float mean = 0.f, rstd = 0.f, gm = 0.f, bt = 0.f;
    if (PASS == 1) {
        float s  = stats[2*c];
        float sq = stats[2*c+1];
        mean = s * (1.0f / (float)NPC);
        float var = sq * (1.0f / (float)NPC) - mean * mean;
        rstd = rsqrtf(var + 1e-5f);
        gm = gamma[c]; bt = beta[c];
    }

    if (PASS == 1 && tile == 3) {
        // entire tile masked to zero pre-BN -> constant after BN
        float v = (0.f - mean) * rstd * gm + bt;
        f32x4 vv = {v, v, v, v};
        float* op = out + (size_t)n * (HD*HD);
        for (int it = 0; it < 16; ++it) {
            int t  = it * 256 + tid;        // 4096 float4 slots in 128x128 region
            int r  = t >> 5;
            int c4 = (t & 31) * 4;
            *(f32x4*)&op[(size_t)(128 + r) * HD + c4] = vv;
        }
        return;
    }

    int ti, tk;
    if      (tile == 0) { ti = 0; tk = 0; }
    else if (tile == 1) { ti = 0; tk = 1; }
    else                { ti = 1; tk = 1; }

    const float* xp = x + (size_t)n * (HD*HD);

    __shared__ short As[128 * 40];   // 128 rows x BK=32, padded to 40 (16B-aligned rows)
    __shared__ short Bs[128 * 40];
    __shared__ float red[512];

    const int wid   = tid >> 6;
    const int lane  = tid & 63;
    const int waveM = wid >> 1, waveN = wid & 1;
    const int lrow  = lane & 15;
    const int lkk   = (lane >> 4) * 8;

    f32x4 acc[4][4];
    for (int i = 0; i < 4; ++i)
        for (int j = 0; j < 4; ++j)
            acc[i][j] = (f32x4){0.f, 0.f, 0.f, 0.f};

    const int rr = tid >> 3;         // 0..31
    const int cc = (tid & 7) * 4;    // 0..28

    for (int kb = 0; kb < 8; ++kb) {
        for (int it = 0; it < 4; ++it) {
            int r = rr + it * 32;
            f32x4 av = *(const f32x4*)&xp[(size_t)(ti*128 + r) * HD + kb*32 + cc];
            f32x4 bv = *(const f32x4*)&xp[(size_t)(tk*128 + r) * HD + kb*32 + cc];
            s16x4 a4 = { f2bf(av.x), f2bf(av.y), f2bf(av.z), f2bf(av.w) };
            s16x4 b4 = { f2bf(bv.x), f2bf(bv.y), f2bf(bv.z), f2bf(bv.w) };
            *(s16x4*)&As[r*40 + cc] = a4;
            *(s16x4*)&Bs[r*40 + cc] = b4;
        }
        __syncthreads();
        s16x8 af[4], bfr[4];
        for (int mi = 0; mi < 4; ++mi)
            af[mi]  = *(s16x8*)&As[(waveM*64 + mi*16 + lrow)*40 + lkk];
        for (int ni = 0; ni < 4; ++ni)
            bfr[ni] = *(s16x8*)&Bs[(waveN*64 + ni*16 + lrow)*40 + lkk];
        for (int mi = 0; mi < 4; ++mi)
            for (int ni = 0; ni < 4; ++ni)
                acc[mi][ni] = __builtin_amdgcn_mfma_f32_16x16x32_bf16(
                    af[mi], bfr[ni], acc[mi][ni], 0, 0, 0);
        __syncthreads();
    }

    // epilogue: mask (k>=i), apply weight, then stats (pass0) or normalize+store (pass1)
    float lsum = 0.f, lsq = 0.f;
    const int row0 = (lane >> 4) * 4;
    const int col0 = lane & 15;
    for (int mi = 0; mi < 4; ++mi) {
        for (int ni = 0; ni < 4; ++ni) {
            int gk = tk*128 + waveN*64 + ni*16 + col0;
            for (int r = 0; r < 4; ++r) {
                int gi = ti*128 + waveM*64 + mi*16 + row0 + r;
                float v = acc[mi][ni][r];
                float val = (gk >= gi)
                    ? v * w[(size_t)c * (HD*HD) + (size_t)gi * HD + gk]
                    : 0.f;
                if (PASS == 0) {
                    lsum += val;
                    lsq  += val * val;
                } else {
                    out[(size_t)n * (HD*HD) + (size_t)gi * HD + gk] =
                        (val - mean) * rstd * gm + bt;
                }
            }
        }
    }

    if (PASS == 0) {
        red[tid]       = lsum;
        red[256 + tid] = lsq;
        __syncthreads();
        for (int s = 128; s > 0; s >>= 1) {
            if (tid < s) {
                red[tid]       += red[tid + s];
                red[256 + tid] += red[256 + tid + s];
            }
            __syncthreads();
        }
        if (tid == 0) {
            atomicAdd(&stats[2*c],     red[0]);
            atomicAdd(&stats[2*c + 1], red[256]);
        }
    }
}

extern "C" void kernel_launch(void* const* d_in, const int* in_sizes, int n_in,
                              void* d_out, int out_size, void* d_ws, size_t ws_size,
                              hipStream_t stream) {
    const float* x     = (const float*)d_in[0];
    const float* w     = (const float*)d_in[1];
    const float* gamma = (const float*)d_in[2];
    const float* beta  = (const float*)d_in[3];
    float* out   = (float*)d_out;
    float* stats = (float*)d_ws;

    // zero the stats accumulators (ws is poisoned before every call)
    hipMemsetAsync(d_ws, 0, 128 * sizeof(float), stream);

    dim3 block(256);
    // pass 0: 3 compute tiles (skip all-masked lower-left) x 16 batches x 64 channels
    gram_bn_kernel<0><<<dim3(3, 16, 64), block, 0, stream>>>(x, w, gamma, beta, out, stats);
    // pass 1: 4 tiles (tile 3 = constant fill) x 16 x 64
    gram_bn_kernel<1><<<dim3(4, 16, 64), block, 0, stream>>>(x, w, gamma, beta, out, stats);
}

// Round 2
// 706.521 us; speedup vs baseline: 1.0638x; 1.0638x over previous
//
#include <hip/hip_runtime.h>

#define HD 256
#define NCH 64
#define NB 16
#define NPLANE (NB * NCH)           // 1024
#define NPC (NB * HD * HD)          // BN population per channel = 1048576
#define PLANE_ELEMS (HD * HD)       // 65536

typedef __attribute__((ext_vector_type(4))) float f32x4;
typedef __attribute__((ext_vector_type(8))) short s16x8;
typedef __attribute__((ext_vector_type(4))) short s16x4;

__device__ __forceinline__ short f2bf(float f) {
    unsigned u = __float_as_uint(f);
    u += 0x7FFFu + ((u >> 16) & 1u);   // round-to-nearest-even
    return (short)(u >> 16);
}

__device__ __forceinline__ void gl2lds16(const void* g, void* l) {
    __builtin_amdgcn_global_load_lds(
        (const __attribute__((address_space(1))) unsigned int*)g,
        (__attribute__((address_space(3))) unsigned int*)l, 16, 0, 0);
}

// ---------------------------------------------------------------- k0: fp32 -> bf16
__global__ __launch_bounds__(256) void convert_kernel(
    const float* __restrict__ x, short* __restrict__ xb)
{
    size_t i = ((size_t)blockIdx.x * 256 + threadIdx.x) * 8;
    f32x4 a = *(const f32x4*)&x[i];
    f32x4 b = *(const f32x4*)&x[i + 4];
    s16x8 o = { f2bf(a.x), f2bf(a.y), f2bf(a.z), f2bf(a.w),
                f2bf(b.x), f2bf(b.y), f2bf(b.z), f2bf(b.w) };
    *(s16x8*)&xb[i] = o;
}

// ---------------------------------------------------------------- k1: Gram*w (masked), store raw + stats
// tiles: 0:(0,0) 1:(0,1) 2:(1,1). Lower-left (1,0) is fully masked -> never computed.
__global__ __launch_bounds__(256) void gram_kernel(
    const short* __restrict__ xb, const float* __restrict__ w,
    float* __restrict__ out, float* __restrict__ stats)
{
    const int tile = blockIdx.x;
    const int b    = blockIdx.y;
    const int c    = blockIdx.z;
    const int n    = b * NCH + c;
    const int tid  = threadIdx.x;

    const int ti = (tile == 2) ? 1 : 0;
    const int tk = (tile == 0) ? 0 : 1;
    const bool diag = (ti == tk);

    // chunk-major LDS: chunk id = q*128 + r  (q = k-subchunk 0..3, r = row 0..127)
    // each chunk = 8 shorts (16B). Fragment read (s16x8) is bank-conflict-free.
    __shared__ short As[4096];
    __shared__ short Bs[4096];
    __shared__ float red[512];

    const short* xpA = xb + (size_t)n * PLANE_ELEMS + (size_t)ti * 128 * HD;
    const short* xpB = xb + (size_t)n * PLANE_ELEMS + (size_t)tk * 128 * HD;

    const int wid   = tid >> 6;
    const int lane  = tid & 63;
    const int waveM = wid >> 1, waveN = wid & 1;
    const int lrow  = lane & 15;
    const int q     = lane >> 4;          // k-subchunk for fragment reads

    f32x4 acc[4][4];
    for (int i = 0; i < 4; ++i)
        for (int j = 0; j < 4; ++j)
            acc[i][j] = (f32x4){0.f, 0.f, 0.f, 0.f};

    // this thread's two staging chunks per matrix
    const int ch0 = tid;            // 0..255
    const int ch1 = tid + 256;      // 256..511
    const int q0 = ch0 >> 7, r0 = ch0 & 127;
    const int q1 = ch1 >> 7, r1 = ch1 & 127;

    for (int kb = 0; kb < 8; ++kb) {
        const int kbase = kb * 32;
        gl2lds16(xpA + (size_t)r0 * HD + kbase + q0 * 8, &As[(ch0 & ~63) * 8]);
        gl2lds16(xpA + (size_t)r1 * HD + kbase + q1 * 8, &As[(ch1 & ~63) * 8]);
        if (!diag) {
            gl2lds16(xpB + (size_t)r0 * HD + kbase + q0 * 8, &Bs[(ch0 & ~63) * 8]);
            gl2lds16(xpB + (size_t)r1 * HD + kbase + q1 * 8, &Bs[(ch1 & ~63) * 8]);
        }
        __syncthreads();

        s16x8 af[4], bfr[4];
        for (int mi = 0; mi < 4; ++mi) {
            int row = waveM * 64 + mi * 16 + lrow;
            af[mi] = *(s16x8*)&As[(q * 128 + row) * 8];
        }
        const short* Bsrc = diag ? As : Bs;
        for (int ni = 0; ni < 4; ++ni) {
            int row = waveN * 64 + ni * 16 + lrow;
            bfr[ni] = *(s16x8*)&Bsrc[(q * 128 + row) * 8];
        }
        for (int mi = 0; mi < 4; ++mi)
            for (int ni = 0; ni < 4; ++ni)
                acc[mi][ni] = __builtin_amdgcn_mfma_f32_16x16x32_bf16(
                    af[mi], bfr[ni], acc[mi][ni], 0, 0, 0);
        __syncthreads();
    }

    // epilogue: mask (k>=i), weight, store raw, accumulate stats
    float lsum = 0.f, lsq = 0.f;
    const int row0 = (lane >> 4) * 4;
    const int col0 = lane & 15;
    for (int mi = 0; mi < 4; ++mi) {
        for (int ni = 0; ni < 4; ++ni) {
            int gk = tk * 128 + waveN * 64 + ni * 16 + col0;
            for (int r = 0; r < 4; ++r) {
                int gi = ti * 128 + waveM * 64 + mi * 16 + row0 + r;
                float v = acc[mi][ni][r];
                float val = (gk >= gi)
                    ? v * w[(size_t)c * PLANE_ELEMS + (size_t)gi * HD + gk]
                    : 0.f;
                lsum += val;
                lsq  += val * val;
                out[(size_t)n * PLANE_ELEMS + (size_t)gi * HD + gk] = val;
            }
        }
    }

    red[tid]       = lsum;
    red[256 + tid] = lsq;
    __syncthreads();
    for (int s = 128; s > 0; s >>= 1) {
        if (tid < s) {
            red[tid]       += red[tid + s];
            red[256 + tid] += red[256 + tid + s];
        }
        __syncthreads();
    }
    if (tid == 0) {
        atomicAdd(&stats[2*c],     red[0]);
        atomicAdd(&stats[2*c + 1], red[256]);
    }
}

// ---------------------------------------------------------------- k2: normalize in place
__global__ __launch_bounds__(256) void bn_kernel(
    const float* __restrict__ gamma, const float* __restrict__ beta,
    float* __restrict__ out, const float* __restrict__ stats)
{
    const int n   = blockIdx.x;     // 0..1023
    const int seg = blockIdx.y;     // 0..15
    const int tid = threadIdx.x;
    const int c   = n & (NCH - 1);

    float s  = stats[2*c];
    float sq = stats[2*c + 1];
    float mean = s * (1.0f / (float)NPC);
    float var  = sq * (1.0f / (float)NPC) - mean * mean;
    float rstd = rsqrtf(var + 1e-5f);
    float scale = rstd * gamma[c];
    float shift = beta[c] - mean * scale;

    float* op = out + (size_t)n * PLANE_ELEMS;
    f32x4 cv = {shift, shift, shift, shift};
    for (int k = 0; k < 4; ++k) {
        int f4 = seg * 1024 + k * 256 + tid;   // float4 index within plane (0..16383)
        int r  = f4 >> 6;
        int c4 = f4 & 63;
        if (r >= 128 && c4 < 32) {
            *(f32x4*)&op[(size_t)f4 * 4] = cv;     // never-computed lower-left: constant
        } else {
            f32x4 v = *(const f32x4*)&op[(size_t)f4 * 4];
            v.x = v.x * scale + shift;
            v.y = v.y * scale + shift;
            v.z = v.z * scale + shift;
            v.w = v.w * scale + shift;
            *(f32x4*)&op[(size_t)f4 * 4] = v;
        }
    }
}

// ---------------------------------------------------------------- fallback (round-1 path, fp32 staging)
template <int PASS>
__global__ __launch_bounds__(256) void gram_bn_fb(
    const float* __restrict__ x, const float* __restrict__ w,
    const float* __restrict__ gamma, const float* __restrict__ beta,
    float* __restrict__ out, float* __restrict__ stats)
{
    const int tile = blockIdx.x;
    const int b    = blockIdx.y;
    const int c    = blockIdx.z;
    const int n    = b * NCH + c;
    const int tid  = threadIdx.x;

    float mean = 0.f, rstd = 0.f, gm = 0.f, bt = 0.f;
    if (PASS == 1) {
        float s  = stats[2*c];
        float sq = stats[2*c+1];
        mean = s * (1.0f / (float)NPC);
        float var = sq * (1.0f / (float)NPC) - mean * mean;
        rstd = rsqrtf(var + 1e-5f);
        gm = gamma[c]; bt = beta[c];
    }
    if (PASS == 1 && tile == 3) {
        float v = (0.f - mean) * rstd * gm + bt;
        f32x4 vv = {v, v, v, v};
        float* op = out + (size_t)n * PLANE_ELEMS;
        for (int it = 0; it < 16; ++it) {
            int t  = it * 256 + tid;
            int r  = t >> 5;
            int c4 = (t & 31) * 4;
            *(f32x4*)&op[(size_t)(128 + r) * HD + c4] = vv;
        }
        return;
    }
    int ti, tk;
    if      (tile == 0) { ti = 0; tk = 0; }
    else if (tile == 1) { ti = 0; tk = 1; }
    else                { ti = 1; tk = 1; }
    const float* xp = x + (size_t)n * PLANE_ELEMS;
    __shared__ short As[128 * 40];
    __shared__ short Bs[128 * 40];
    __shared__ float red[512];
    const int wid   = tid >> 6;
    const int lane  = tid & 63;
    const int waveM = wid >> 1, waveN = wid & 1;
    const int lrow  = lane & 15;
    const int lkk   = (lane >> 4) * 8;
    f32x4 acc[4][4];
    for (int i = 0; i < 4; ++i)
        for (int j = 0; j < 4; ++j)
            acc[i][j] = (f32x4){0.f, 0.f, 0.f, 0.f};
    const int rr = tid >> 3;
    const int cc = (tid & 7) * 4;
    for (int kb = 0; kb < 8; ++kb) {
        for (int it = 0; it < 4; ++it) {
            int r = rr + it * 32;
            f32x4 av = *(const f32x4*)&xp[(size_t)(ti*128 + r) * HD + kb*32 + cc];
            f32x4 bv = *(const f32x4*)&xp[(size_t)(tk*128 + r) * HD + kb*32 + cc];
            s16x4 a4 = { f2bf(av.x), f2bf(av.y), f2bf(av.z), f2bf(av.w) };
            s16x4 b4 = { f2bf(bv.x), f2bf(bv.y), f2bf(bv.z), f2bf(bv.w) };
            *(s16x4*)&As[r*40 + cc] = a4;
            *(s16x4*)&Bs[r*40 + cc] = b4;
        }
        __syncthreads();
        s16x8 af[4], bfr[4];
        for (int mi = 0; mi < 4; ++mi)
            af[mi]  = *(s16x8*)&As[(waveM*64 + mi*16 + lrow)*40 + lkk];
        for (int ni = 0; ni < 4; ++ni)
            bfr[ni] = *(s16x8*)&Bs[(waveN*64 + ni*16 + lrow)*40 + lkk];
        for (int mi = 0; mi < 4; ++mi)
            for (int ni = 0; ni < 4; ++ni)
                acc[mi][ni] = __builtin_amdgcn_mfma_f32_16x16x32_bf16(
                    af[mi], bfr[ni], acc[mi][ni], 0, 0, 0);
        __syncthreads();
    }
    float lsum = 0.f, lsq = 0.f;
    const int row0 = (lane >> 4) * 4;
    const int col0 = lane & 15;
    for (int mi = 0; mi < 4; ++mi) {
        for (int ni = 0; ni < 4; ++ni) {
            int gk = tk*128 + waveN*64 + ni*16 + col0;
            for (int r = 0; r < 4; ++r) {
                int gi = ti*128 + waveM*64 + mi*16 + row0 + r;
                float v = acc[mi][ni][r];
                float val = (gk >= gi)
                    ? v * w[(size_t)c * PLANE_ELEMS + (size_t)gi * HD + gk]
                    : 0.f;
                if (PASS == 0) { lsum += val; lsq += val * val; }
                else out[(size_t)n * PLANE_ELEMS + (size_t)gi * HD + gk] =
                        (val - mean) * rstd * gm + bt;
            }
        }
    }
    if (PASS == 0) {
        red[tid] = lsum; red[256 + tid] = lsq;
        __syncthreads();
        for (int s = 128; s > 0; s >>= 1) {
            if (tid < s) { red[tid] += red[tid+s]; red[256+tid] += red[256+tid+s]; }
            __syncthreads();
        }
        if (tid == 0) {
            atomicAdd(&stats[2*c],     red[0]);
            atomicAdd(&stats[2*c + 1], red[256]);
        }
    }
}

extern "C" void kernel_launch(void* const* d_in, const int* in_sizes, int n_in,
                              void* d_out, int out_size, void* d_ws, size_t ws_size,
                              hipStream_t stream) {
    const float* x     = (const float*)d_in[0];
    const float* w     = (const float*)d_in[1];
    const float* gamma = (const float*)d_in[2];
    const float* beta  = (const float*)d_in[3];
    float* out   = (float*)d_out;
    float* stats = (float*)d_ws;

    hipMemsetAsync(d_ws, 0, 128 * sizeof(float), stream);

    const size_t xb_bytes = (size_t)NPLANE * PLANE_ELEMS * sizeof(short); // 128 MiB
    if (ws_size >= 1024 + xb_bytes) {
        short* xb = (short*)((char*)d_ws + 1024);
        convert_kernel<<<dim3(32768), dim3(256), 0, stream>>>(x, xb);
        gram_kernel<<<dim3(3, NB, NCH), dim3(256), 0, stream>>>(xb, w, out, stats);
        bn_kernel<<<dim3(NPLANE, 16), dim3(256), 0, stream>>>(gamma, beta, out, stats);
    } else {
        gram_bn_fb<0><<<dim3(3, NB, NCH), dim3(256), 0, stream>>>(x, w, gamma, beta, out, stats);
        gram_bn_fb<1><<<dim3(4, NB, NCH), dim3(256), 0, stream>>>(x, w, gamma, beta, out, stats);
    }
}